// Round 1
// baseline (288075.439 us; speedup 1.0000x reference)
//
#include <hip/hip_runtime.h>
#include <hip/hip_cooperative_groups.h>

namespace cg = cooperative_groups;

#define Bb 64
#define Tt 256
#define Dd 1024
#define Hh 1024
#define HMm 256
#define Ee 64

__device__ __forceinline__ float b2f(unsigned short u){
    union{unsigned int i; float f;} v; v.i = ((unsigned int)u) << 16; return v.f;
}
__device__ __forceinline__ unsigned short f2bf(float f){
    union{float f; unsigned int i;} v; v.f = f;
    unsigned int x = v.i;
    unsigned int r = (x + 0x7fffu + ((x >> 16) & 1u)) >> 16;
    return (unsigned short)r;
}
__device__ __forceinline__ void up2(unsigned int u, float& lo, float& hi){
    union{unsigned int i; float f;} x, y;
    x.i = u << 16; y.i = u & 0xffff0000u; lo = x.f; hi = y.f;
}
__device__ __forceinline__ float sigf(float x){ return 1.f/(1.f + expf(-x)); }

__device__ __forceinline__ float ldT(const unsigned short* p){ return b2f(*p); }
__device__ __forceinline__ float ldT(const float* p){ return *p; }
__device__ __forceinline__ void stT(unsigned short* p, float v){ *p = f2bf(v); }
__device__ __forceinline__ void stT(float* p, float v){ *p = v; }

__device__ __forceinline__ void ld8(const unsigned short* p, float* f){
    uint4 u = *(const uint4*)(const void*)p;
    up2(u.x,f[0],f[1]); up2(u.y,f[2],f[3]); up2(u.z,f[4],f[5]); up2(u.w,f[6],f[7]);
}
__device__ __forceinline__ void ld8(const float* p, float* f){
    float4 a = *(const float4*)(const void*)p;
    float4 b = *(const float4*)(const void*)(p+4);
    f[0]=a.x; f[1]=a.y; f[2]=a.z; f[3]=a.w; f[4]=b.x; f[5]=b.y; f[6]=b.z; f[7]=b.w;
}
__device__ __forceinline__ float dot8(const float* a, const float* b, float acc){
    #pragma unroll
    for(int i=0;i<8;i++) acc += a[i]*b[i];
    return acc;
}

// ---- dtype probe: even-indexed u16 as bf16 is ~N(0,1) iff buffer is bf16 ----
__global__ void k_detect(const unsigned short* __restrict__ x, int* __restrict__ flag){
    int tid = threadIdx.x;
    float v = fabsf(b2f(x[2 * tid]));
    bool in = (v > 1e-4f) && (v < 50.f);
    unsigned long long m = __ballot(in);
    if(tid == 0) *flag = (__popcll(m) >= 32) ? 0 : 1;  // 0 = bf16, 1 = f32
}

// Persistent cooperative kernel: whole 2-layer meta-LSTM in one launch.
// grid 256 x block 1024 (16 waves/CU = 4 waves/SIMD for latency hiding).
// 3 grid syncs per timestep. Work split: each phase K-split 4-way (ks in
// lane bits 0-1) with __shfl_xor / LDS reduction; all global layouts and
// per-lane ld8 patterns identical to the verified 256-thread kernel.
// ws floats: h0(64K) h1(64K) c(64K) mh0(16K) mh1(16K) mc(16K) z(48K) xbuf(64K) | flag
template<typename T>
__global__ __launch_bounds__(1024, 4) void coop_rnn(
    const T* x,
    const T* __restrict__ Wx, const T* __restrict__ Wh,
    const T* __restrict__ Wmx, const T* __restrict__ Wmh, const T* __restrict__ bm,
    const T* __restrict__ Wzx, const T* __restrict__ bzx,
    const T* __restrict__ Wzh, const T* __restrict__ bzh, const T* __restrict__ Wzb,
    const T* __restrict__ Px, const T* __restrict__ Ph, const T* __restrict__ Pb,
    T* out, float* ws, const int* flag)
{
    if(*flag != (int)(sizeof(T) == 4)) return;   // uniform across grid: dead path exits before any sync
    cg::grid_group grid = cg::this_grid();

    float* h0   = ws;
    float* h1   = ws + 65536;
    float* cst  = ws + 131072;
    float* m0   = ws + 196608;
    float* m1   = ws + 212992;
    float* mcst = ws + 229376;
    float* z    = ws + 245760;   // 49152
    float* xbuf = ws + 294912;   // 65536

    int tid = threadIdx.x, bid = blockIdx.x;

    __shared__ float sA[256];
    __shared__ float spre[1024];

    for(int l = 0; l < 2; l++){
        const T* xseq = l ? out : x;
        const T* Wx_l  = Wx  + (size_t)l * 4194304;
        const T* Wh_l  = Wh  + (size_t)l * 4194304;
        const T* Wmx_l = Wmx + (size_t)l * 2097152;
        const T* Wmh_l = Wmh + (size_t)l * 262144;
        const T* bm_l  = bm  + l * 1024;
        const T* Wz0 = Wzx + l * 65536;
        const T* Wz1 = Wzh + l * 65536;
        const T* Wz2 = Wzb + l * 65536;
        const T* bz0 = bzx + l * 256;
        const T* bz1 = bzh + l * 256;
        const T* Px_l = Px + l * 262144;
        const T* Ph_l = Ph + l * 262144;
        const T* Pb_l = Pb + l * 262144;

        // zero states (hp=h0, mp=m0 at layer start; 256 steps is even so
        // pointers return to h0/m0 after each layer)
        {
            int gid = bid * 1024 + tid;          // 262144 threads
            if(gid < 65536){ h0[gid] = 0.f; cst[gid] = 0.f; }
            if(gid < 16384){ m0[gid] = 0.f; mcst[gid] = 0.f; }
        }
        float *hp = h0, *hn = h1, *mp = m0, *mn = m1;
        grid.sync();

        for(int t = 0; t < 256; t++){
            // ======== PHASE A: meta GEMM (4-way K-split) + meta-LSTM; stage xbuf ========
            {
                // stage x[:,t,:] -> xbuf (f32): blocks 0..63, one elem/thread
                int sg = bid * 1024 + tid;
                if(sg < 65536){
                    int xb = sg >> 10, xd = sg & 1023;
                    xbuf[sg] = ldT(&xseq[((size_t)xb * Tt + t) * Dd + xd]);
                }

                int r  = tid >> 8;             // gate 0..3 (wave-uniform)
                int b  = (tid >> 2) & 63;      // batch
                int ks = tid & 3;              // K-split (lane bits 0-1)
                int row = r * 256 + bid;
                const T* wr = Wmx_l + (size_t)row * 2048;  // [x-part | h-part]
                const T* wm = Wmh_l + (size_t)row * 256;
                const T* xr = xseq + ((size_t)b * Tt + t) * Dd;
                const float* hr = hp + b * 1024;
                const float* mr = mp + b * 256;
                float a0 = 0.f, a1 = 0.f, a2 = 0.f, a3 = 0.f;
                float wf[8], vf[8];
                int k0 = ks * 256;
                for(int k = k0; k < k0 + 256; k += 16){
                    ld8(wr + k, wf);      ld8(xr + k, vf);      a0 = dot8(wf, vf, a0);
                    ld8(wr + k + 8, wf);  ld8(xr + k + 8, vf);  a1 = dot8(wf, vf, a1);
                }
                for(int k = k0; k < k0 + 256; k += 16){
                    ld8(wr + 1024 + k, wf);     ld8(hr + k, vf);     a2 = dot8(wf, vf, a2);
                    ld8(wr + 1024 + k + 8, wf); ld8(hr + k + 8, vf); a3 = dot8(wf, vf, a3);
                }
                int ms = ks * 64;
                for(int m = ms; m < ms + 64; m += 16){
                    ld8(wm + m, wf);     ld8(mr + m, vf);     a0 = dot8(wf, vf, a0);
                    ld8(wm + m + 8, wf); ld8(mr + m + 8, vf); a1 = dot8(wf, vf, a1);
                }
                float a = (a0 + a1) + (a2 + a3);
                a += __shfl_xor(a, 1);
                a += __shfl_xor(a, 2);
                if(ks == 0) sA[r * 64 + b] = a + ldT(&bm_l[row]);
            }
            __syncthreads();
            if(tid < 64){
                int b = tid;
                float mi = sA[b], mf = sA[64 + b], mg = sA[128 + b], mo = sA[192 + b];
                int idx = b * 256 + bid;
                float mc2 = sigf(mf) * mcst[idx] + sigf(mi) * tanhf(mg);
                mcst[idx] = mc2;
                mn[idx] = sigf(mo) * tanhf(mc2);
            }
            grid.sync();

            // ======== PHASE Z: z[s,b,col] = bias + mh2[b,:] @ Wz[:,col] (4-way m-split) ========
            if(bid < 192){
                int s_ = bid >> 6, b = bid & 63;
                int ks = tid >> 8, col = tid & 255;
                const T* W = (s_ == 0) ? Wz0 : ((s_ == 1) ? Wz1 : Wz2);
                const float* mr = mn + b * 256;
                float acc = 0.f;
                int ms = ks * 64;
                #pragma unroll 8
                for(int m = ms; m < ms + 64; m++)
                    acc += mr[m] * ldT(&W[m * 256 + col]);
                spre[tid] = acc;
                __syncthreads();
                if(tid < 256){
                    float biasv = (s_ == 0) ? ldT(&bz0[tid]) : ((s_ == 1) ? ldT(&bz1[tid]) : 0.f);
                    z[(s_ * 64 + b) * 256 + tid] =
                        biasv + ((spre[tid] + spre[256 + tid]) + (spre[512 + tid] + spre[768 + tid]));
                }
            }
            grid.sync();

            // ======== PHASE B: pre = dx*gx + dh*gh + db (4-way K-split); LSTM update ========
            {
                int r16 = tid >> 6;            // g*4+hh (wave-uniform)
                int g = r16 >> 2, hh = r16 & 3;
                int bg = (tid >> 2) & 15;      // batch group (4 batches each)
                int ks = tid & 3;              // K-split (lane bits 0-1)
                int h = bid * 4 + hh;
                int n = g * 1024 + h;          // row of Wx/Wh (4,H,K)
                int b0 = bg * 4;
                const T* wxr = Wx_l + (size_t)n * 1024;
                const T* whr = Wh_l + (size_t)n * 1024;
                float gx[4] = {0,0,0,0}, gh[4] = {0,0,0,0};
                int k0 = ks * 256;
                for(int k = k0; k < k0 + 256; k += 8){
                    float wf[8]; ld8(wxr + k, wf);
                    #pragma unroll
                    for(int i = 0; i < 4; i++){
                        float xf[8]; ld8(xbuf + (b0 + i) * 1024 + k, xf);
                        gx[i] = dot8(wf, xf, gx[i]);
                    }
                }
                for(int k = k0; k < k0 + 256; k += 8){
                    float wf[8]; ld8(whr + k, wf);
                    #pragma unroll
                    for(int i = 0; i < 4; i++){
                        float hf[8]; ld8(hp + (b0 + i) * 1024 + k, hf);
                        gh[i] = dot8(wf, hf, gh[i]);
                    }
                }
                float dx[4] = {0,0,0,0}, dh[4] = {0,0,0,0}, db[4] = {0,0,0,0};
                int e0 = ks * 16;
                for(int e = e0; e < e0 + 16; e++){
                    int pi = (g * 64 + e) * 1024 + h;
                    float pxv = ldT(&Px_l[pi]);
                    float phv = ldT(&Ph_l[pi]);
                    float pbv = ldT(&Pb_l[pi]);
                    int zc = g * 64 + e;
                    #pragma unroll
                    for(int i = 0; i < 4; i++){
                        int b = b0 + i;
                        dx[i] += z[(b) * 256 + zc] * pxv;
                        dh[i] += z[(64 + b) * 256 + zc] * phv;
                        db[i] += z[(128 + b) * 256 + zc] * pbv;
                    }
                }
                // reduce the 5 partial families over ks (lanes differ in bits 0-1).
                // NOTE: dx/gx etc. must be reduced separately — pre is a product
                // of full reductions, partial products are NOT summable.
                #pragma unroll
                for(int i = 0; i < 4; i++){
                    gx[i] += __shfl_xor(gx[i], 1); gx[i] += __shfl_xor(gx[i], 2);
                    gh[i] += __shfl_xor(gh[i], 1); gh[i] += __shfl_xor(gh[i], 2);
                    dx[i] += __shfl_xor(dx[i], 1); dx[i] += __shfl_xor(dx[i], 2);
                    dh[i] += __shfl_xor(dh[i], 1); dh[i] += __shfl_xor(dh[i], 2);
                    db[i] += __shfl_xor(db[i], 1); db[i] += __shfl_xor(db[i], 2);
                }
                if(ks == 0){
                    #pragma unroll
                    for(int i = 0; i < 4; i++)
                        spre[r16 * 64 + b0 + i] = dx[i] * gx[i] + dh[i] * gh[i] + db[i];
                }
            }
            __syncthreads();
            if(tid < 256){
                int hh = tid >> 6, b = tid & 63;
                float pi_ = spre[(0 * 4 + hh) * 64 + b];
                float pf_ = spre[(1 * 4 + hh) * 64 + b];
                float pg_ = spre[(2 * 4 + hh) * 64 + b];
                float po_ = spre[(3 * 4 + hh) * 64 + b];
                int h = bid * 4 + hh;
                int idx = b * 1024 + h;
                float c2 = sigf(pf_) * cst[idx] + sigf(pi_) * tanhf(pg_);
                float h2 = sigf(po_) * tanhf(c2);
                cst[idx] = c2;
                hn[idx] = h2;
                stT(&out[((size_t)b * Tt + t) * Dd + h], h2);
            }
            grid.sync();

            float* tp = hp; hp = hn; hn = tp;
            tp = mp; mp = mn; mn = tp;
        }
    }
}

template<typename T>
static void launch_path(void* const* d_in, void* d_out, float* ws, int* flag, hipStream_t stream){
    const T* xp   = (const T*)d_in[0];
    const T* Wxp  = (const T*)d_in[1];
    const T* Whp  = (const T*)d_in[2];
    const T* Wmxp = (const T*)d_in[3];
    const T* Wmhp = (const T*)d_in[4];
    const T* bmp  = (const T*)d_in[5];
    const T* Wzxp = (const T*)d_in[6];
    const T* bzxp = (const T*)d_in[7];
    const T* Wzhp = (const T*)d_in[8];
    const T* bzhp = (const T*)d_in[9];
    const T* Wzbp = (const T*)d_in[10];
    const T* Pxp  = (const T*)d_in[11];
    const T* Php  = (const T*)d_in[12];
    const T* Pbp  = (const T*)d_in[13];
    T* outp = (T*)d_out;
    void* args[] = {
        (void*)&xp, (void*)&Wxp, (void*)&Whp, (void*)&Wmxp, (void*)&Wmhp, (void*)&bmp,
        (void*)&Wzxp, (void*)&bzxp, (void*)&Wzhp, (void*)&bzhp, (void*)&Wzbp,
        (void*)&Pxp, (void*)&Php, (void*)&Pbp, (void*)&outp, (void*)&ws, (void*)&flag
    };
    hipLaunchCooperativeKernel((void*)coop_rnn<T>, dim3(256), dim3(1024), args, 0, stream);
}

extern "C" void kernel_launch(void* const* d_in, const int* in_sizes, int n_in,
                              void* d_out, int out_size, void* d_ws, size_t ws_size,
                              hipStream_t stream) {
    (void)in_sizes; (void)n_in; (void)out_size; (void)ws_size;
    float* ws = (float*)d_ws;
    int* flag = (int*)(ws + 360448);

    k_detect<<<1, 64, 0, stream>>>((const unsigned short*)d_in[0], flag);
    launch_path<unsigned short>(d_in, d_out, ws, flag, stream);
    launch_path<float>(d_in, d_out, ws, flag, stream);
}

// Round 2
// 287746.826 us; speedup vs baseline: 1.0011x; 1.0011x over previous
//
#include <hip/hip_runtime.h>
#include <hip/hip_cooperative_groups.h>

namespace cg = cooperative_groups;

#define Bb 64
#define Tt 256
#define Dd 1024
#define Hh 1024
#define HMm 256
#define Ee 64

__device__ __forceinline__ float b2f(unsigned short u){
    union{unsigned int i; float f;} v; v.i = ((unsigned int)u) << 16; return v.f;
}
__device__ __forceinline__ unsigned short f2bf(float f){
    union{float f; unsigned int i;} v; v.f = f;
    unsigned int x = v.i;
    unsigned int r = (x + 0x7fffu + ((x >> 16) & 1u)) >> 16;
    return (unsigned short)r;
}
__device__ __forceinline__ void up2(unsigned int u, float& lo, float& hi){
    union{unsigned int i; float f;} x, y;
    x.i = u << 16; y.i = u & 0xffff0000u; lo = x.f; hi = y.f;
}
__device__ __forceinline__ float sigf(float x){ return 1.f/(1.f + expf(-x)); }

__device__ __forceinline__ float ldT(const unsigned short* p){ return b2f(*p); }
__device__ __forceinline__ float ldT(const float* p){ return *p; }
__device__ __forceinline__ void stT(unsigned short* p, float v){ *p = f2bf(v); }
__device__ __forceinline__ void stT(float* p, float v){ *p = v; }

__device__ __forceinline__ void ld8(const unsigned short* p, float* f){
    uint4 u = *(const uint4*)(const void*)p;
    up2(u.x,f[0],f[1]); up2(u.y,f[2],f[3]); up2(u.z,f[4],f[5]); up2(u.w,f[6],f[7]);
}
__device__ __forceinline__ void ld8(const float* p, float* f){
    float4 a = *(const float4*)(const void*)p;
    float4 b = *(const float4*)(const void*)(p+4);
    f[0]=a.x; f[1]=a.y; f[2]=a.z; f[3]=a.w; f[4]=b.x; f[5]=b.y; f[6]=b.z; f[7]=b.w;
}
__device__ __forceinline__ float dot8(const float* a, const float* b, float acc){
    #pragma unroll
    for(int i=0;i<8;i++) acc += a[i]*b[i];
    return acc;
}

// ---- dtype probe: even-indexed u16 as bf16 is ~N(0,1) iff buffer is bf16 ----
__global__ void k_detect(const unsigned short* __restrict__ x, int* __restrict__ flag){
    int tid = threadIdx.x;
    float v = fabsf(b2f(x[2 * tid]));
    bool in = (v > 1e-4f) && (v < 50.f);
    unsigned long long m = __ballot(in);
    if(tid == 0) *flag = (__popcll(m) >= 32) ? 0 : 1;  // 0 = bf16, 1 = f32
}

// ============================================================================
// BF16 path: weights cached in LDS (once per layer). ~100 KB LDS/block,
// 1 block/CU, 16 waves/CU. Only activations cross the grid.sync L2-invalidate
// boundary. z stored transposed [3][256][64] for float4 reads in phase B.
// ws floats: h0(64K) h1(64K) c(64K) mh0(16K) mh1(16K) mc(16K) z(48K) xbuf(64K) | flag
// ============================================================================
__global__ __launch_bounds__(1024, 4) void coop_rnn_bf16(
    const unsigned short* x,
    const unsigned short* __restrict__ Wx, const unsigned short* __restrict__ Wh,
    const unsigned short* __restrict__ Wmx, const unsigned short* __restrict__ Wmh,
    const unsigned short* __restrict__ bm,
    const unsigned short* __restrict__ Wzx, const unsigned short* __restrict__ bzx,
    const unsigned short* __restrict__ Wzh, const unsigned short* __restrict__ bzh,
    const unsigned short* __restrict__ Wzb,
    const unsigned short* __restrict__ Px, const unsigned short* __restrict__ Ph,
    const unsigned short* __restrict__ Pb,
    unsigned short* out, float* ws, const int* flag)
{
    if(*flag != 0) return;   // uniform across grid
    cg::grid_group grid = cg::this_grid();

    float* h0   = ws;
    float* h1   = ws + 65536;
    float* cst  = ws + 131072;
    float* m0   = ws + 196608;
    float* m1   = ws + 212992;
    float* mcst = ws + 229376;
    float* z    = ws + 245760;                         // [3][256][64] f32
    unsigned short* xbuf16 = (unsigned short*)(ws + 294912);  // 65536 u16

    int tid = threadIdx.x, bid = blockIdx.x;

    // ---- LDS: per-block weight slice (bf16), padded K-chunks (+8 elems)
    // so the 4 ks lanes land 4 banks apart (528B/144B strides). ~100 KB.
    __shared__ __align__(16) unsigned short sWx[16][4][264];
    __shared__ __align__(16) unsigned short sWh[16][4][264];
    __shared__ __align__(16) unsigned short sWmxX[4][4][264];
    __shared__ __align__(16) unsigned short sWmxH[4][4][264];
    __shared__ __align__(16) unsigned short sWmh[4][4][72];
    __shared__ __align__(16) unsigned short sWz[3][4][72];
    __shared__ __align__(16) unsigned short sP[3][4][64][4];
    __shared__ float sBm[4], sBz[2];
    __shared__ float sA[256];
    __shared__ float spre[1024];

    for(int l = 0; l < 2; l++){
        const unsigned short* xseq = l ? out : x;
        const unsigned short* Wx_l  = Wx  + (size_t)l * 4194304;
        const unsigned short* Wh_l  = Wh  + (size_t)l * 4194304;
        const unsigned short* Wmx_l = Wmx + (size_t)l * 2097152;
        const unsigned short* Wmh_l = Wmh + (size_t)l * 262144;
        const unsigned short* bm_l  = bm  + l * 1024;
        const unsigned short* Wz0 = Wzx + l * 65536;
        const unsigned short* Wz1 = Wzh + l * 65536;
        const unsigned short* Wz2 = Wzb + l * 65536;
        const unsigned short* bz0 = bzx + l * 256;
        const unsigned short* bz1 = bzh + l * 256;
        const unsigned short* Px_l = Px + l * 262144;
        const unsigned short* Ph_l = Ph + l * 262144;
        const unsigned short* Pb_l = Pb + l * 262144;

        // ---- zero states ----
        {
            int gid = bid * 1024 + tid;
            if(gid < 65536){ h0[gid] = 0.f; cst[gid] = 0.f; }
            if(gid < 16384){ m0[gid] = 0.f; mcst[gid] = 0.f; }
        }

        // ---- fill LDS weight slice (once per layer; raw bf16 copies) ----
        for(int idx = tid; idx < 16384; idx += 1024){      // Wx rows g*1024+bid*4+hh
            int rr = idx >> 10, k = idx & 1023;
            int g = rr >> 2, hh = rr & 3;
            size_t n = (size_t)(g * 1024 + bid * 4 + hh);
            sWx[rr][k >> 8][k & 255] = Wx_l[n * 1024 + k];
        }
        for(int idx = tid; idx < 16384; idx += 1024){      // Wh same rows
            int rr = idx >> 10, k = idx & 1023;
            int g = rr >> 2, hh = rr & 3;
            size_t n = (size_t)(g * 1024 + bid * 4 + hh);
            sWh[rr][k >> 8][k & 255] = Wh_l[n * 1024 + k];
        }
        for(int idx = tid; idx < 4096; idx += 1024){       // Wmx rows r*256+bid
            int r = idx >> 10, k = idx & 1023;
            size_t row = (size_t)(r * 256 + bid);
            sWmxX[r][k >> 8][k & 255] = Wmx_l[row * 2048 + k];
            sWmxH[r][k >> 8][k & 255] = Wmx_l[row * 2048 + 1024 + k];
        }
        {                                                  // Wmh: 4 rows x 256
            int r = tid >> 8, m = tid & 255;
            sWmh[r][m >> 6][m & 63] = Wmh_l[(size_t)(r * 256 + bid) * 256 + m];
        }
        if(tid < 768){                                     // Wz columns bid
            int s_ = tid >> 8, m = tid & 255;
            const unsigned short* W = (s_ == 0) ? Wz0 : ((s_ == 1) ? Wz1 : Wz2);
            sWz[s_][m >> 6][m & 63] = W[m * 256 + bid];
        }
        {                                                  // P slice cols bid*4..+3
            int g = tid >> 8, e = (tid >> 2) & 63, hh = tid & 3;
            int pi = (g * 64 + e) * 1024 + bid * 4 + hh;
            sP[0][g][e][hh] = Px_l[pi];
            sP[1][g][e][hh] = Ph_l[pi];
            sP[2][g][e][hh] = Pb_l[pi];
        }
        if(tid < 4) sBm[tid] = ldT(&bm_l[tid * 256 + bid]);
        if(tid == 4) sBz[0] = ldT(&bz0[bid]);
        if(tid == 5) sBz[1] = ldT(&bz1[bid]);

        float *hp = h0, *hn = h1, *mp = m0, *mn = m1;
        grid.sync();

        for(int t = 0; t < 256; t++){
            // ======== PHASE A: meta GEMM (LDS weights, 4-way ks) + stage xbuf ========
            {
                int sg = bid * 1024 + tid;
                if(sg < 65536){
                    int xb = sg >> 10, xd = sg & 1023;
                    xbuf16[sg] = xseq[((size_t)xb * Tt + t) * Dd + xd];  // raw bf16
                }

                int r  = tid >> 8;             // gate (wave-uniform)
                int b  = (tid >> 2) & 63;      // batch
                int ks = tid & 3;              // K-split (lane bits 0-1)
                const unsigned short* wxp = &sWmxX[r][ks][0];
                const unsigned short* whp_ = &sWmxH[r][ks][0];
                const unsigned short* wmp = &sWmh[r][ks][0];
                const unsigned short* xr = xseq + ((size_t)b * Tt + t) * Dd + ks * 256;
                const float* hr = hp + b * 1024 + ks * 256;
                const float* mr = mp + b * 256 + ks * 64;
                float a0 = 0.f, a1 = 0.f, a2 = 0.f, a3 = 0.f;
                float wf[8], vf[8];
                for(int k = 0; k < 256; k += 16){
                    ld8(wxp + k, wf);     ld8(xr + k, vf);     a0 = dot8(wf, vf, a0);
                    ld8(wxp + k + 8, wf); ld8(xr + k + 8, vf); a1 = dot8(wf, vf, a1);
                }
                for(int k = 0; k < 256; k += 16){
                    ld8(whp_ + k, wf);     ld8(hr + k, vf);     a2 = dot8(wf, vf, a2);
                    ld8(whp_ + k + 8, wf); ld8(hr + k + 8, vf); a3 = dot8(wf, vf, a3);
                }
                for(int m = 0; m < 64; m += 16){
                    ld8(wmp + m, wf);     ld8(mr + m, vf);     a0 = dot8(wf, vf, a0);
                    ld8(wmp + m + 8, wf); ld8(mr + m + 8, vf); a1 = dot8(wf, vf, a1);
                }
                float a = (a0 + a1) + (a2 + a3);
                a += __shfl_xor(a, 1);
                a += __shfl_xor(a, 2);
                if(ks == 0) sA[r * 64 + b] = a + sBm[r];
            }
            __syncthreads();
            if(tid < 64){
                int b = tid;
                float mi = sA[b], mf = sA[64 + b], mg = sA[128 + b], mo = sA[192 + b];
                int idx = b * 256 + bid;
                float mc2 = sigf(mf) * mcst[idx] + sigf(mi) * tanhf(mg);
                mcst[idx] = mc2;
                mn[idx] = sigf(mo) * tanhf(mc2);
            }
            grid.sync();

            // ======== PHASE Z: block bid owns column bid; z[s][col][b] ========
            if(tid < 768){
                int s_ = tid >> 8, sub = tid & 255;
                int b = sub >> 2, ks = sub & 3;
                const unsigned short* wz = &sWz[s_][ks][0];
                const float* mr = mn + b * 256 + ks * 64;
                float acc = 0.f; float wf[8], vf[8];
                for(int m = 0; m < 64; m += 16){
                    ld8(wz + m, wf);     ld8(mr + m, vf);     acc = dot8(wf, vf, acc);
                    ld8(wz + m + 8, wf); ld8(mr + m + 8, vf); acc = dot8(wf, vf, acc);
                }
                acc += __shfl_xor(acc, 1);
                acc += __shfl_xor(acc, 2);
                if(ks == 0){
                    float biasv = (s_ == 0) ? sBz[0] : ((s_ == 1) ? sBz[1] : 0.f);
                    z[((s_ * 256) + bid) * 64 + b] = acc + biasv;
                }
            }
            grid.sync();

            // ======== PHASE B: pre = dx*gx + dh*gh + db (LDS weights) ========
            {
                int r16 = tid >> 6;            // g*4+hh (wave-uniform)
                int g = r16 >> 2, hh = r16 & 3;
                int bg = (tid >> 2) & 15;
                int ks = tid & 3;
                int b0 = bg * 4;
                const unsigned short* wxr = &sWx[r16][ks][0];
                const unsigned short* whr = &sWh[r16][ks][0];
                float gx[4] = {0,0,0,0}, gh[4] = {0,0,0,0};
                for(int k = 0; k < 256; k += 8){
                    float wf[8]; ld8(wxr + k, wf);
                    #pragma unroll
                    for(int i = 0; i < 4; i++){
                        float xf[8]; ld8(xbuf16 + (b0 + i) * 1024 + ks * 256 + k, xf);
                        gx[i] = dot8(wf, xf, gx[i]);
                    }
                }
                for(int k = 0; k < 256; k += 8){
                    float wf[8]; ld8(whr + k, wf);
                    #pragma unroll
                    for(int i = 0; i < 4; i++){
                        float hf[8]; ld8(hp + (b0 + i) * 1024 + ks * 256 + k, hf);
                        gh[i] = dot8(wf, hf, gh[i]);
                    }
                }
                float dx[4] = {0,0,0,0}, dh[4] = {0,0,0,0}, db[4] = {0,0,0,0};
                int e0 = ks * 16;
                for(int e = e0; e < e0 + 16; e++){
                    int zc = g * 64 + e;
                    float pxv = b2f(sP[0][g][e][hh]);
                    float phv = b2f(sP[1][g][e][hh]);
                    float pbv = b2f(sP[2][g][e][hh]);
                    const float4 zx4 = *(const float4*)&z[(0 * 256 + zc) * 64 + b0];
                    const float4 zh4 = *(const float4*)&z[(1 * 256 + zc) * 64 + b0];
                    const float4 zb4 = *(const float4*)&z[(2 * 256 + zc) * 64 + b0];
                    dx[0] += zx4.x * pxv; dx[1] += zx4.y * pxv; dx[2] += zx4.z * pxv; dx[3] += zx4.w * pxv;
                    dh[0] += zh4.x * phv; dh[1] += zh4.y * phv; dh[2] += zh4.z * phv; dh[3] += zh4.w * phv;
                    db[0] += zb4.x * pbv; db[1] += zb4.y * pbv; db[2] += zb4.z * pbv; db[3] += zb4.w * pbv;
                }
                // reduce the 5 partial families over ks (lane bits 0-1):
                // products of full sums, so each family reduced separately.
                #pragma unroll
                for(int i = 0; i < 4; i++){
                    gx[i] += __shfl_xor(gx[i], 1); gx[i] += __shfl_xor(gx[i], 2);
                    gh[i] += __shfl_xor(gh[i], 1); gh[i] += __shfl_xor(gh[i], 2);
                    dx[i] += __shfl_xor(dx[i], 1); dx[i] += __shfl_xor(dx[i], 2);
                    dh[i] += __shfl_xor(dh[i], 1); dh[i] += __shfl_xor(dh[i], 2);
                    db[i] += __shfl_xor(db[i], 1); db[i] += __shfl_xor(db[i], 2);
                }
                if(ks == 0){
                    #pragma unroll
                    for(int i = 0; i < 4; i++)
                        spre[r16 * 64 + b0 + i] = dx[i] * gx[i] + dh[i] * gh[i] + db[i];
                }
            }
            __syncthreads();
            if(tid < 256){
                int hh = tid >> 6, b = tid & 63;
                float pi_ = spre[(0 * 4 + hh) * 64 + b];
                float pf_ = spre[(1 * 4 + hh) * 64 + b];
                float pg_ = spre[(2 * 4 + hh) * 64 + b];
                float po_ = spre[(3 * 4 + hh) * 64 + b];
                int h = bid * 4 + hh;
                int idx = b * 1024 + h;
                float c2 = sigf(pf_) * cst[idx] + sigf(pi_) * tanhf(pg_);
                float h2 = sigf(po_) * tanhf(c2);
                cst[idx] = c2;
                hn[idx] = h2;
                stT(&out[((size_t)b * Tt + t) * Dd + h], h2);
            }
            grid.sync();

            float* tp = hp; hp = hn; hn = tp;
            tp = mp; mp = mn; mn = tp;
        }
    }
}

// ============================================================================
// F32 fallback path — verified legacy code (global weight reads), unchanged.
// ============================================================================
__global__ __launch_bounds__(1024, 4) void coop_rnn_f32(
    const float* x,
    const float* __restrict__ Wx, const float* __restrict__ Wh,
    const float* __restrict__ Wmx, const float* __restrict__ Wmh, const float* __restrict__ bm,
    const float* __restrict__ Wzx, const float* __restrict__ bzx,
    const float* __restrict__ Wzh, const float* __restrict__ bzh, const float* __restrict__ Wzb,
    const float* __restrict__ Px, const float* __restrict__ Ph, const float* __restrict__ Pb,
    float* out, float* ws, const int* flag)
{
    if(*flag != 1) return;
    cg::grid_group grid = cg::this_grid();

    float* h0   = ws;
    float* h1   = ws + 65536;
    float* cst  = ws + 131072;
    float* m0   = ws + 196608;
    float* m1   = ws + 212992;
    float* mcst = ws + 229376;
    float* z    = ws + 245760;
    float* xbuf = ws + 294912;

    int tid = threadIdx.x, bid = blockIdx.x;

    __shared__ float sA[256];
    __shared__ float spre[1024];

    for(int l = 0; l < 2; l++){
        const float* xseq = l ? out : x;
        const float* Wx_l  = Wx  + (size_t)l * 4194304;
        const float* Wh_l  = Wh  + (size_t)l * 4194304;
        const float* Wmx_l = Wmx + (size_t)l * 2097152;
        const float* Wmh_l = Wmh + (size_t)l * 262144;
        const float* bm_l  = bm  + l * 1024;
        const float* Wz0 = Wzx + l * 65536;
        const float* Wz1 = Wzh + l * 65536;
        const float* Wz2 = Wzb + l * 65536;
        const float* bz0 = bzx + l * 256;
        const float* bz1 = bzh + l * 256;
        const float* Px_l = Px + l * 262144;
        const float* Ph_l = Ph + l * 262144;
        const float* Pb_l = Pb + l * 262144;

        {
            int gid = bid * 1024 + tid;
            if(gid < 65536){ h0[gid] = 0.f; cst[gid] = 0.f; }
            if(gid < 16384){ m0[gid] = 0.f; mcst[gid] = 0.f; }
        }
        float *hp = h0, *hn = h1, *mp = m0, *mn = m1;
        grid.sync();

        for(int t = 0; t < 256; t++){
            {
                int sg = bid * 1024 + tid;
                if(sg < 65536){
                    int xb = sg >> 10, xd = sg & 1023;
                    xbuf[sg] = ldT(&xseq[((size_t)xb * Tt + t) * Dd + xd]);
                }
                int r  = tid >> 8;
                int b  = (tid >> 2) & 63;
                int ks = tid & 3;
                int row = r * 256 + bid;
                const float* wr = Wmx_l + (size_t)row * 2048;
                const float* wm = Wmh_l + (size_t)row * 256;
                const float* xr = xseq + ((size_t)b * Tt + t) * Dd;
                const float* hr = hp + b * 1024;
                const float* mr = mp + b * 256;
                float a0 = 0.f, a1 = 0.f, a2 = 0.f, a3 = 0.f;
                float wf[8], vf[8];
                int k0 = ks * 256;
                for(int k = k0; k < k0 + 256; k += 16){
                    ld8(wr + k, wf);      ld8(xr + k, vf);      a0 = dot8(wf, vf, a0);
                    ld8(wr + k + 8, wf);  ld8(xr + k + 8, vf);  a1 = dot8(wf, vf, a1);
                }
                for(int k = k0; k < k0 + 256; k += 16){
                    ld8(wr + 1024 + k, wf);     ld8(hr + k, vf);     a2 = dot8(wf, vf, a2);
                    ld8(wr + 1024 + k + 8, wf); ld8(hr + k + 8, vf); a3 = dot8(wf, vf, a3);
                }
                int ms = ks * 64;
                for(int m = ms; m < ms + 64; m += 16){
                    ld8(wm + m, wf);     ld8(mr + m, vf);     a0 = dot8(wf, vf, a0);
                    ld8(wm + m + 8, wf); ld8(mr + m + 8, vf); a1 = dot8(wf, vf, a1);
                }
                float a = (a0 + a1) + (a2 + a3);
                a += __shfl_xor(a, 1);
                a += __shfl_xor(a, 2);
                if(ks == 0) sA[r * 64 + b] = a + ldT(&bm_l[row]);
            }
            __syncthreads();
            if(tid < 64){
                int b = tid;
                float mi = sA[b], mf = sA[64 + b], mg = sA[128 + b], mo = sA[192 + b];
                int idx = b * 256 + bid;
                float mc2 = sigf(mf) * mcst[idx] + sigf(mi) * tanhf(mg);
                mcst[idx] = mc2;
                mn[idx] = sigf(mo) * tanhf(mc2);
            }
            grid.sync();

            if(bid < 192){
                int s_ = bid >> 6, b = bid & 63;
                int ks = tid >> 8, col = tid & 255;
                const float* W = (s_ == 0) ? Wz0 : ((s_ == 1) ? Wz1 : Wz2);
                const float* mr = mn + b * 256;
                float acc = 0.f;
                int ms = ks * 64;
                #pragma unroll 8
                for(int m = ms; m < ms + 64; m++)
                    acc += mr[m] * ldT(&W[m * 256 + col]);
                spre[tid] = acc;
                __syncthreads();
                if(tid < 256){
                    float biasv = (s_ == 0) ? ldT(&bz0[tid]) : ((s_ == 1) ? ldT(&bz1[tid]) : 0.f);
                    z[(s_ * 64 + b) * 256 + tid] =
                        biasv + ((spre[tid] + spre[256 + tid]) + (spre[512 + tid] + spre[768 + tid]));
                }
            }
            grid.sync();

            {
                int r16 = tid >> 6;
                int g = r16 >> 2, hh = r16 & 3;
                int bg = (tid >> 2) & 15;
                int ks = tid & 3;
                int h = bid * 4 + hh;
                int n = g * 1024 + h;
                int b0 = bg * 4;
                const float* wxr = Wx_l + (size_t)n * 1024;
                const float* whr = Wh_l + (size_t)n * 1024;
                float gx[4] = {0,0,0,0}, gh[4] = {0,0,0,0};
                int k0 = ks * 256;
                for(int k = k0; k < k0 + 256; k += 8){
                    float wf[8]; ld8(wxr + k, wf);
                    #pragma unroll
                    for(int i = 0; i < 4; i++){
                        float xf[8]; ld8(xbuf + (b0 + i) * 1024 + k, xf);
                        gx[i] = dot8(wf, xf, gx[i]);
                    }
                }
                for(int k = k0; k < k0 + 256; k += 8){
                    float wf[8]; ld8(whr + k, wf);
                    #pragma unroll
                    for(int i = 0; i < 4; i++){
                        float hf[8]; ld8(hp + (b0 + i) * 1024 + k, hf);
                        gh[i] = dot8(wf, hf, gh[i]);
                    }
                }
                float dx[4] = {0,0,0,0}, dh[4] = {0,0,0,0}, db[4] = {0,0,0,0};
                int e0 = ks * 16;
                for(int e = e0; e < e0 + 16; e++){
                    int pi = (g * 64 + e) * 1024 + h;
                    float pxv = ldT(&Px_l[pi]);
                    float phv = ldT(&Ph_l[pi]);
                    float pbv = ldT(&Pb_l[pi]);
                    int zc = g * 64 + e;
                    #pragma unroll
                    for(int i = 0; i < 4; i++){
                        int b = b0 + i;
                        dx[i] += z[(b) * 256 + zc] * pxv;
                        dh[i] += z[(64 + b) * 256 + zc] * phv;
                        db[i] += z[(128 + b) * 256 + zc] * pbv;
                    }
                }
                #pragma unroll
                for(int i = 0; i < 4; i++){
                    gx[i] += __shfl_xor(gx[i], 1); gx[i] += __shfl_xor(gx[i], 2);
                    gh[i] += __shfl_xor(gh[i], 1); gh[i] += __shfl_xor(gh[i], 2);
                    dx[i] += __shfl_xor(dx[i], 1); dx[i] += __shfl_xor(dx[i], 2);
                    dh[i] += __shfl_xor(dh[i], 1); dh[i] += __shfl_xor(dh[i], 2);
                    db[i] += __shfl_xor(db[i], 1); db[i] += __shfl_xor(db[i], 2);
                }
                if(ks == 0){
                    #pragma unroll
                    for(int i = 0; i < 4; i++)
                        spre[r16 * 64 + b0 + i] = dx[i] * gx[i] + dh[i] * gh[i] + db[i];
                }
            }
            __syncthreads();
            if(tid < 256){
                int hh = tid >> 6, b = tid & 63;
                float pi_ = spre[(0 * 4 + hh) * 64 + b];
                float pf_ = spre[(1 * 4 + hh) * 64 + b];
                float pg_ = spre[(2 * 4 + hh) * 64 + b];
                float po_ = spre[(3 * 4 + hh) * 64 + b];
                int h = bid * 4 + hh;
                int idx = b * 1024 + h;
                float c2 = sigf(pf_) * cst[idx] + sigf(pi_) * tanhf(pg_);
                float h2 = sigf(po_) * tanhf(c2);
                cst[idx] = c2;
                hn[idx] = h2;
                stT(&out[((size_t)b * Tt + t) * Dd + h], h2);
            }
            grid.sync();

            float* tp = hp; hp = hn; hn = tp;
            tp = mp; mp = mn; mn = tp;
        }
    }
}

static void launch_bf16(void* const* d_in, void* d_out, float* ws, int* flag, hipStream_t stream){
    const unsigned short* xp   = (const unsigned short*)d_in[0];
    const unsigned short* Wxp  = (const unsigned short*)d_in[1];
    const unsigned short* Whp  = (const unsigned short*)d_in[2];
    const unsigned short* Wmxp = (const unsigned short*)d_in[3];
    const unsigned short* Wmhp = (const unsigned short*)d_in[4];
    const unsigned short* bmp  = (const unsigned short*)d_in[5];
    const unsigned short* Wzxp = (const unsigned short*)d_in[6];
    const unsigned short* bzxp = (const unsigned short*)d_in[7];
    const unsigned short* Wzhp = (const unsigned short*)d_in[8];
    const unsigned short* bzhp = (const unsigned short*)d_in[9];
    const unsigned short* Wzbp = (const unsigned short*)d_in[10];
    const unsigned short* Pxp  = (const unsigned short*)d_in[11];
    const unsigned short* Php  = (const unsigned short*)d_in[12];
    const unsigned short* Pbp  = (const unsigned short*)d_in[13];
    unsigned short* outp = (unsigned short*)d_out;
    void* args[] = {
        (void*)&xp, (void*)&Wxp, (void*)&Whp, (void*)&Wmxp, (void*)&Wmhp, (void*)&bmp,
        (void*)&Wzxp, (void*)&bzxp, (void*)&Wzhp, (void*)&bzhp, (void*)&Wzbp,
        (void*)&Pxp, (void*)&Php, (void*)&Pbp, (void*)&outp, (void*)&ws, (void*)&flag
    };
    hipLaunchCooperativeKernel((void*)coop_rnn_bf16, dim3(256), dim3(1024), args, 0, stream);
}

static void launch_f32(void* const* d_in, void* d_out, float* ws, int* flag, hipStream_t stream){
    const float* xp   = (const float*)d_in[0];
    const float* Wxp  = (const float*)d_in[1];
    const float* Whp  = (const float*)d_in[2];
    const float* Wmxp = (const float*)d_in[3];
    const float* Wmhp = (const float*)d_in[4];
    const float* bmp  = (const float*)d_in[5];
    const float* Wzxp = (const float*)d_in[6];
    const float* bzxp = (const float*)d_in[7];
    const float* Wzhp = (const float*)d_in[8];
    const float* bzhp = (const float*)d_in[9];
    const float* Wzbp = (const float*)d_in[10];
    const float* Pxp  = (const float*)d_in[11];
    const float* Php  = (const float*)d_in[12];
    const float* Pbp  = (const float*)d_in[13];
    float* outp = (float*)d_out;
    void* args[] = {
        (void*)&xp, (void*)&Wxp, (void*)&Whp, (void*)&Wmxp, (void*)&Wmhp, (void*)&bmp,
        (void*)&Wzxp, (void*)&bzxp, (void*)&Wzhp, (void*)&bzhp, (void*)&Wzbp,
        (void*)&Pxp, (void*)&Php, (void*)&Pbp, (void*)&outp, (void*)&ws, (void*)&flag
    };
    hipLaunchCooperativeKernel((void*)coop_rnn_f32, dim3(256), dim3(1024), args, 0, stream);
}

extern "C" void kernel_launch(void* const* d_in, const int* in_sizes, int n_in,
                              void* d_out, int out_size, void* d_ws, size_t ws_size,
                              hipStream_t stream) {
    (void)in_sizes; (void)n_in; (void)out_size; (void)ws_size;
    float* ws = (float*)d_ws;
    int* flag = (int*)(ws + 360448);

    k_detect<<<1, 64, 0, stream>>>((const unsigned short*)d_in[0], flag);
    launch_bf16(d_in, d_out, ws, flag, stream);
    launch_f32(d_in, d_out, ws, flag, stream);
}

// Round 3
// 252821.118 us; speedup vs baseline: 1.1394x; 1.1381x over previous
//
#include <hip/hip_runtime.h>
#include <hip/hip_cooperative_groups.h>

namespace cg = cooperative_groups;

#define Bb 64
#define Tt 256
#define Dd 1024
#define Hh 1024
#define HMm 256
#define Ee 64

__device__ __forceinline__ float b2f(unsigned short u){
    union{unsigned int i; float f;} v; v.i = ((unsigned int)u) << 16; return v.f;
}
__device__ __forceinline__ unsigned short f2bf(float f){
    union{float f; unsigned int i;} v; v.f = f;
    unsigned int x = v.i;
    unsigned int r = (x + 0x7fffu + ((x >> 16) & 1u)) >> 16;
    return (unsigned short)r;
}
__device__ __forceinline__ void up2(unsigned int u, float& lo, float& hi){
    union{unsigned int i; float f;} x, y;
    x.i = u << 16; y.i = u & 0xffff0000u; lo = x.f; hi = y.f;
}
__device__ __forceinline__ float sigf(float x){ return 1.f/(1.f + expf(-x)); }

__device__ __forceinline__ float ldT(const unsigned short* p){ return b2f(*p); }
__device__ __forceinline__ float ldT(const float* p){ return *p; }
__device__ __forceinline__ void stT(unsigned short* p, float v){ *p = f2bf(v); }
__device__ __forceinline__ void stT(float* p, float v){ *p = v; }

__device__ __forceinline__ void ld8(const unsigned short* p, float* f){
    uint4 u = *(const uint4*)(const void*)p;
    up2(u.x,f[0],f[1]); up2(u.y,f[2],f[3]); up2(u.z,f[4],f[5]); up2(u.w,f[6],f[7]);
}
__device__ __forceinline__ void ld8(const float* p, float* f){
    float4 a = *(const float4*)(const void*)p;
    float4 b = *(const float4*)(const void*)(p+4);
    f[0]=a.x; f[1]=a.y; f[2]=a.z; f[3]=a.w; f[4]=b.x; f[5]=b.y; f[6]=b.z; f[7]=b.w;
}
__device__ __forceinline__ float dot8(const float* a, const float* b, float acc){
    #pragma unroll
    for(int i=0;i<8;i++) acc += a[i]*b[i];
    return acc;
}

// ---- dtype probe: even-indexed u16 as bf16 is ~N(0,1) iff buffer is bf16 ----
__global__ void k_detect(const unsigned short* __restrict__ x, int* __restrict__ flag){
    int tid = threadIdx.x;
    float v = fabsf(b2f(x[2 * tid]));
    bool in = (v > 1e-4f) && (v < 50.f);
    unsigned long long m = __ballot(in);
    if(tid == 0) *flag = (__popcll(m) >= 32) ? 0 : 1;  // 0 = bf16, 1 = f32
}

// ============================================================================
// BF16 path (kept from previous round; does not run for f32 harness inputs).
// ============================================================================
__global__ __launch_bounds__(1024, 4) void coop_rnn_bf16(
    const unsigned short* x,
    const unsigned short* __restrict__ Wx, const unsigned short* __restrict__ Wh,
    const unsigned short* __restrict__ Wmx, const unsigned short* __restrict__ Wmh,
    const unsigned short* __restrict__ bm,
    const unsigned short* __restrict__ Wzx, const unsigned short* __restrict__ bzx,
    const unsigned short* __restrict__ Wzh, const unsigned short* __restrict__ bzh,
    const unsigned short* __restrict__ Wzb,
    const unsigned short* __restrict__ Px, const unsigned short* __restrict__ Ph,
    const unsigned short* __restrict__ Pb,
    unsigned short* out, float* ws, const int* flag)
{
    if(*flag != 0) return;   // uniform across grid
    cg::grid_group grid = cg::this_grid();

    float* h0   = ws;
    float* h1   = ws + 65536;
    float* cst  = ws + 131072;
    float* m0   = ws + 196608;
    float* m1   = ws + 212992;
    float* mcst = ws + 229376;
    float* z    = ws + 245760;                         // [3][256][64] f32
    unsigned short* xbuf16 = (unsigned short*)(ws + 294912);  // 65536 u16

    int tid = threadIdx.x, bid = blockIdx.x;

    __shared__ __align__(16) unsigned short sWx[16][4][264];
    __shared__ __align__(16) unsigned short sWh[16][4][264];
    __shared__ __align__(16) unsigned short sWmxX[4][4][264];
    __shared__ __align__(16) unsigned short sWmxH[4][4][264];
    __shared__ __align__(16) unsigned short sWmh[4][4][72];
    __shared__ __align__(16) unsigned short sWz[3][4][72];
    __shared__ __align__(16) unsigned short sP[3][4][64][4];
    __shared__ float sBm[4], sBz[2];
    __shared__ float sA[256];
    __shared__ float spre[1024];

    for(int l = 0; l < 2; l++){
        const unsigned short* xseq = l ? out : x;
        const unsigned short* Wx_l  = Wx  + (size_t)l * 4194304;
        const unsigned short* Wh_l  = Wh  + (size_t)l * 4194304;
        const unsigned short* Wmx_l = Wmx + (size_t)l * 2097152;
        const unsigned short* Wmh_l = Wmh + (size_t)l * 262144;
        const unsigned short* bm_l  = bm  + l * 1024;
        const unsigned short* Wz0 = Wzx + l * 65536;
        const unsigned short* Wz1 = Wzh + l * 65536;
        const unsigned short* Wz2 = Wzb + l * 65536;
        const unsigned short* bz0 = bzx + l * 256;
        const unsigned short* bz1 = bzh + l * 256;
        const unsigned short* Px_l = Px + l * 262144;
        const unsigned short* Ph_l = Ph + l * 262144;
        const unsigned short* Pb_l = Pb + l * 262144;

        {
            int gid = bid * 1024 + tid;
            if(gid < 65536){ h0[gid] = 0.f; cst[gid] = 0.f; }
            if(gid < 16384){ m0[gid] = 0.f; mcst[gid] = 0.f; }
        }

        for(int idx = tid; idx < 16384; idx += 1024){
            int rr = idx >> 10, k = idx & 1023;
            int g = rr >> 2, hh = rr & 3;
            size_t n = (size_t)(g * 1024 + bid * 4 + hh);
            sWx[rr][k >> 8][k & 255] = Wx_l[n * 1024 + k];
        }
        for(int idx = tid; idx < 16384; idx += 1024){
            int rr = idx >> 10, k = idx & 1023;
            int g = rr >> 2, hh = rr & 3;
            size_t n = (size_t)(g * 1024 + bid * 4 + hh);
            sWh[rr][k >> 8][k & 255] = Wh_l[n * 1024 + k];
        }
        for(int idx = tid; idx < 4096; idx += 1024){
            int r = idx >> 10, k = idx & 1023;
            size_t row = (size_t)(r * 256 + bid);
            sWmxX[r][k >> 8][k & 255] = Wmx_l[row * 2048 + k];
            sWmxH[r][k >> 8][k & 255] = Wmx_l[row * 2048 + 1024 + k];
        }
        {
            int r = tid >> 8, m = tid & 255;
            sWmh[r][m >> 6][m & 63] = Wmh_l[(size_t)(r * 256 + bid) * 256 + m];
        }
        if(tid < 768){
            int s_ = tid >> 8, m = tid & 255;
            const unsigned short* W = (s_ == 0) ? Wz0 : ((s_ == 1) ? Wz1 : Wz2);
            sWz[s_][m >> 6][m & 63] = W[m * 256 + bid];
        }
        {
            int g = tid >> 8, e = (tid >> 2) & 63, hh = tid & 3;
            int pi = (g * 64 + e) * 1024 + bid * 4 + hh;
            sP[0][g][e][hh] = Px_l[pi];
            sP[1][g][e][hh] = Ph_l[pi];
            sP[2][g][e][hh] = Pb_l[pi];
        }
        if(tid < 4) sBm[tid] = ldT(&bm_l[tid * 256 + bid]);
        if(tid == 4) sBz[0] = ldT(&bz0[bid]);
        if(tid == 5) sBz[1] = ldT(&bz1[bid]);

        float *hp = h0, *hn = h1, *mp = m0, *mn = m1;
        grid.sync();

        for(int t = 0; t < 256; t++){
            {
                int sg = bid * 1024 + tid;
                if(sg < 65536){
                    int xb = sg >> 10, xd = sg & 1023;
                    xbuf16[sg] = xseq[((size_t)xb * Tt + t) * Dd + xd];
                }

                int r  = tid >> 8;
                int b  = (tid >> 2) & 63;
                int ks = tid & 3;
                const unsigned short* wxp = &sWmxX[r][ks][0];
                const unsigned short* whp_ = &sWmxH[r][ks][0];
                const unsigned short* wmp = &sWmh[r][ks][0];
                const unsigned short* xr = xseq + ((size_t)b * Tt + t) * Dd + ks * 256;
                const float* hr = hp + b * 1024 + ks * 256;
                const float* mr = mp + b * 256 + ks * 64;
                float a0 = 0.f, a1 = 0.f, a2 = 0.f, a3 = 0.f;
                float wf[8], vf[8];
                for(int k = 0; k < 256; k += 16){
                    ld8(wxp + k, wf);     ld8(xr + k, vf);     a0 = dot8(wf, vf, a0);
                    ld8(wxp + k + 8, wf); ld8(xr + k + 8, vf); a1 = dot8(wf, vf, a1);
                }
                for(int k = 0; k < 256; k += 16){
                    ld8(whp_ + k, wf);     ld8(hr + k, vf);     a2 = dot8(wf, vf, a2);
                    ld8(whp_ + k + 8, wf); ld8(hr + k + 8, vf); a3 = dot8(wf, vf, a3);
                }
                for(int m = 0; m < 64; m += 16){
                    ld8(wmp + m, wf);     ld8(mr + m, vf);     a0 = dot8(wf, vf, a0);
                    ld8(wmp + m + 8, wf); ld8(mr + m + 8, vf); a1 = dot8(wf, vf, a1);
                }
                float a = (a0 + a1) + (a2 + a3);
                a += __shfl_xor(a, 1);
                a += __shfl_xor(a, 2);
                if(ks == 0) sA[r * 64 + b] = a + sBm[r];
            }
            __syncthreads();
            if(tid < 64){
                int b = tid;
                float mi = sA[b], mf = sA[64 + b], mg = sA[128 + b], mo = sA[192 + b];
                int idx = b * 256 + bid;
                float mc2 = sigf(mf) * mcst[idx] + sigf(mi) * tanhf(mg);
                mcst[idx] = mc2;
                mn[idx] = sigf(mo) * tanhf(mc2);
            }
            grid.sync();

            if(tid < 768){
                int s_ = tid >> 8, sub = tid & 255;
                int b = sub >> 2, ks = sub & 3;
                const unsigned short* wz = &sWz[s_][ks][0];
                const float* mr = mn + b * 256 + ks * 64;
                float acc = 0.f; float wf[8], vf[8];
                for(int m = 0; m < 64; m += 16){
                    ld8(wz + m, wf);     ld8(mr + m, vf);     acc = dot8(wf, vf, acc);
                    ld8(wz + m + 8, wf); ld8(mr + m + 8, vf); acc = dot8(wf, vf, acc);
                }
                acc += __shfl_xor(acc, 1);
                acc += __shfl_xor(acc, 2);
                if(ks == 0){
                    float biasv = (s_ == 0) ? sBz[0] : ((s_ == 1) ? sBz[1] : 0.f);
                    z[((s_ * 256) + bid) * 64 + b] = acc + biasv;
                }
            }
            grid.sync();

            {
                int r16 = tid >> 6;
                int g = r16 >> 2, hh = r16 & 3;
                int bg = (tid >> 2) & 15;
                int ks = tid & 3;
                int b0 = bg * 4;
                const unsigned short* wxr = &sWx[r16][ks][0];
                const unsigned short* whr = &sWh[r16][ks][0];
                float gx[4] = {0,0,0,0}, gh[4] = {0,0,0,0};
                for(int k = 0; k < 256; k += 8){
                    float wf[8]; ld8(wxr + k, wf);
                    #pragma unroll
                    for(int i = 0; i < 4; i++){
                        float xf[8]; ld8(xbuf16 + (b0 + i) * 1024 + ks * 256 + k, xf);
                        gx[i] = dot8(wf, xf, gx[i]);
                    }
                }
                for(int k = 0; k < 256; k += 8){
                    float wf[8]; ld8(whr + k, wf);
                    #pragma unroll
                    for(int i = 0; i < 4; i++){
                        float hf[8]; ld8(hp + (b0 + i) * 1024 + ks * 256 + k, hf);
                        gh[i] = dot8(wf, hf, gh[i]);
                    }
                }
                float dx[4] = {0,0,0,0}, dh[4] = {0,0,0,0}, db[4] = {0,0,0,0};
                int e0 = ks * 16;
                for(int e = e0; e < e0 + 16; e++){
                    int zc = g * 64 + e;
                    float pxv = b2f(sP[0][g][e][hh]);
                    float phv = b2f(sP[1][g][e][hh]);
                    float pbv = b2f(sP[2][g][e][hh]);
                    const float4 zx4 = *(const float4*)&z[(0 * 256 + zc) * 64 + b0];
                    const float4 zh4 = *(const float4*)&z[(1 * 256 + zc) * 64 + b0];
                    const float4 zb4 = *(const float4*)&z[(2 * 256 + zc) * 64 + b0];
                    dx[0] += zx4.x * pxv; dx[1] += zx4.y * pxv; dx[2] += zx4.z * pxv; dx[3] += zx4.w * pxv;
                    dh[0] += zh4.x * phv; dh[1] += zh4.y * phv; dh[2] += zh4.z * phv; dh[3] += zh4.w * phv;
                    db[0] += zb4.x * pbv; db[1] += zb4.y * pbv; db[2] += zb4.z * pbv; db[3] += zb4.w * pbv;
                }
                #pragma unroll
                for(int i = 0; i < 4; i++){
                    gx[i] += __shfl_xor(gx[i], 1); gx[i] += __shfl_xor(gx[i], 2);
                    gh[i] += __shfl_xor(gh[i], 1); gh[i] += __shfl_xor(gh[i], 2);
                    dx[i] += __shfl_xor(dx[i], 1); dx[i] += __shfl_xor(dx[i], 2);
                    dh[i] += __shfl_xor(dh[i], 1); dh[i] += __shfl_xor(dh[i], 2);
                    db[i] += __shfl_xor(db[i], 1); db[i] += __shfl_xor(db[i], 2);
                }
                if(ks == 0){
                    #pragma unroll
                    for(int i = 0; i < 4; i++)
                        spre[r16 * 64 + b0 + i] = dx[i] * gx[i] + dh[i] * gh[i] + db[i];
                }
            }
            __syncthreads();
            if(tid < 256){
                int hh = tid >> 6, b = tid & 63;
                float pi_ = spre[(0 * 4 + hh) * 64 + b];
                float pf_ = spre[(1 * 4 + hh) * 64 + b];
                float pg_ = spre[(2 * 4 + hh) * 64 + b];
                float po_ = spre[(3 * 4 + hh) * 64 + b];
                int h = bid * 4 + hh;
                int idx = b * 1024 + h;
                float c2 = sigf(pf_) * cst[idx] + sigf(pi_) * tanhf(pg_);
                float h2 = sigf(po_) * tanhf(c2);
                cst[idx] = c2;
                hn[idx] = h2;
                stT(&out[((size_t)b * Tt + t) * Dd + h], h2);
            }
            grid.sync();

            float* tp = hp; hp = hn; hn = tp;
            tp = mp; mp = mn; mn = tp;
        }
    }
}

// ============================================================================
// F32 path — THE PATH THAT RUNS. Now with per-block f32 LDS weight caches
// for phase B (Wx, Wh, P slices). Numerics bit-identical to the verified
// kernel: same values, same accumulation order — only the load source moves
// from global (re-fetched past L2 every grid.sync) to LDS (filled once/layer).
// LDS: sWx 66K + sWh 66K + sP 15K + sA 1K + spre 4K ~= 152 KB (< 160 KB/CU).
// ks-chunk stride 264 f32 = 1056 B -> banks 0/8/16/24: conflict-free ld8.
// ============================================================================
__global__ __launch_bounds__(1024, 4) void coop_rnn_f32(
    const float* x,
    const float* __restrict__ Wx, const float* __restrict__ Wh,
    const float* __restrict__ Wmx, const float* __restrict__ Wmh, const float* __restrict__ bm,
    const float* __restrict__ Wzx, const float* __restrict__ bzx,
    const float* __restrict__ Wzh, const float* __restrict__ bzh, const float* __restrict__ Wzb,
    const float* __restrict__ Px, const float* __restrict__ Ph, const float* __restrict__ Pb,
    float* out, float* ws, const int* flag)
{
    if(*flag != 1) return;
    cg::grid_group grid = cg::this_grid();

    float* h0   = ws;
    float* h1   = ws + 65536;
    float* cst  = ws + 131072;
    float* m0   = ws + 196608;
    float* m1   = ws + 212992;
    float* mcst = ws + 229376;
    float* z    = ws + 245760;
    float* xbuf = ws + 294912;

    int tid = threadIdx.x, bid = blockIdx.x;

    __shared__ __align__(16) float sWx[16][4][264];   // 67,584 B
    __shared__ __align__(16) float sWh[16][4][264];   // 67,584 B
    __shared__ __align__(16) float sP[3][4][64][5];   // 15,360 B (pad 5: ks 2-way = free)
    __shared__ float sA[256];
    __shared__ float spre[1024];

    for(int l = 0; l < 2; l++){
        const float* xseq = l ? out : x;
        const float* Wx_l  = Wx  + (size_t)l * 4194304;
        const float* Wh_l  = Wh  + (size_t)l * 4194304;
        const float* Wmx_l = Wmx + (size_t)l * 2097152;
        const float* Wmh_l = Wmh + (size_t)l * 262144;
        const float* bm_l  = bm  + l * 1024;
        const float* Wz0 = Wzx + l * 65536;
        const float* Wz1 = Wzh + l * 65536;
        const float* Wz2 = Wzb + l * 65536;
        const float* bz0 = bzx + l * 256;
        const float* bz1 = bzh + l * 256;
        const float* Px_l = Px + l * 262144;
        const float* Ph_l = Ph + l * 262144;
        const float* Pb_l = Pb + l * 262144;

        {
            int gid = bid * 1024 + tid;
            if(gid < 65536){ h0[gid] = 0.f; cst[gid] = 0.f; }
            if(gid < 16384){ m0[gid] = 0.f; mcst[gid] = 0.f; }
        }

        // ---- fill LDS weight slices (once per layer; f32, bit-exact) ----
        for(int idx = tid; idx < 16384; idx += 1024){
            int rr = idx >> 10, k = idx & 1023;
            int g = rr >> 2, hh = rr & 3;
            size_t n = (size_t)(g * 1024 + bid * 4 + hh);
            sWx[rr][k >> 8][k & 255] = Wx_l[n * 1024 + k];
            sWh[rr][k >> 8][k & 255] = Wh_l[n * 1024 + k];
        }
        {
            int g = tid >> 8, e = (tid >> 2) & 63, hh = tid & 3;
            int pi = (g * 64 + e) * 1024 + bid * 4 + hh;
            sP[0][g][e][hh] = Px_l[pi];
            sP[1][g][e][hh] = Ph_l[pi];
            sP[2][g][e][hh] = Pb_l[pi];
        }

        float *hp = h0, *hn = h1, *mp = m0, *mn = m1;
        grid.sync();

        for(int t = 0; t < 256; t++){
            // ======== PHASE A: meta GEMM (global Wmx/Wmh) + stage xbuf ========
            {
                int sg = bid * 1024 + tid;
                if(sg < 65536){
                    int xb = sg >> 10, xd = sg & 1023;
                    xbuf[sg] = ldT(&xseq[((size_t)xb * Tt + t) * Dd + xd]);
                }
                int r  = tid >> 8;
                int b  = (tid >> 2) & 63;
                int ks = tid & 3;
                int row = r * 256 + bid;
                const float* wr = Wmx_l + (size_t)row * 2048;
                const float* wm = Wmh_l + (size_t)row * 256;
                const float* xr = xseq + ((size_t)b * Tt + t) * Dd;
                const float* hr = hp + b * 1024;
                const float* mr = mp + b * 256;
                float a0 = 0.f, a1 = 0.f, a2 = 0.f, a3 = 0.f;
                float wf[8], vf[8];
                int k0 = ks * 256;
                for(int k = k0; k < k0 + 256; k += 16){
                    ld8(wr + k, wf);      ld8(xr + k, vf);      a0 = dot8(wf, vf, a0);
                    ld8(wr + k + 8, wf);  ld8(xr + k + 8, vf);  a1 = dot8(wf, vf, a1);
                }
                for(int k = k0; k < k0 + 256; k += 16){
                    ld8(wr + 1024 + k, wf);     ld8(hr + k, vf);     a2 = dot8(wf, vf, a2);
                    ld8(wr + 1024 + k + 8, wf); ld8(hr + k + 8, vf); a3 = dot8(wf, vf, a3);
                }
                int ms = ks * 64;
                for(int m = ms; m < ms + 64; m += 16){
                    ld8(wm + m, wf);     ld8(mr + m, vf);     a0 = dot8(wf, vf, a0);
                    ld8(wm + m + 8, wf); ld8(mr + m + 8, vf); a1 = dot8(wf, vf, a1);
                }
                float a = (a0 + a1) + (a2 + a3);
                a += __shfl_xor(a, 1);
                a += __shfl_xor(a, 2);
                if(ks == 0) sA[r * 64 + b] = a + ldT(&bm_l[row]);
            }
            __syncthreads();
            if(tid < 64){
                int b = tid;
                float mi = sA[b], mf = sA[64 + b], mg = sA[128 + b], mo = sA[192 + b];
                int idx = b * 256 + bid;
                float mc2 = sigf(mf) * mcst[idx] + sigf(mi) * tanhf(mg);
                mcst[idx] = mc2;
                mn[idx] = sigf(mo) * tanhf(mc2);
            }
            grid.sync();

            // ======== PHASE Z (unchanged) ========
            if(bid < 192){
                int s_ = bid >> 6, b = bid & 63;
                int ks = tid >> 8, col = tid & 255;
                const float* W = (s_ == 0) ? Wz0 : ((s_ == 1) ? Wz1 : Wz2);
                const float* mr = mn + b * 256;
                float acc = 0.f;
                int ms = ks * 64;
                #pragma unroll 8
                for(int m = ms; m < ms + 64; m++)
                    acc += mr[m] * ldT(&W[m * 256 + col]);
                spre[tid] = acc;
                __syncthreads();
                if(tid < 256){
                    float biasv = (s_ == 0) ? ldT(&bz0[tid]) : ((s_ == 1) ? ldT(&bz1[tid]) : 0.f);
                    z[(s_ * 64 + b) * 256 + tid] =
                        biasv + ((spre[tid] + spre[256 + tid]) + (spre[512 + tid] + spre[768 + tid]));
                }
            }
            grid.sync();

            // ======== PHASE B: LDS weights (bit-identical math) ========
            {
                int r16 = tid >> 6;
                int g = r16 >> 2, hh = r16 & 3;
                int bg = (tid >> 2) & 15;
                int ks = tid & 3;
                int b0 = bg * 4;
                const float* wxr = &sWx[r16][ks][0];
                const float* whr = &sWh[r16][ks][0];
                float gx[4] = {0,0,0,0}, gh[4] = {0,0,0,0};
                for(int k = 0; k < 256; k += 8){
                    float wf[8]; ld8(wxr + k, wf);
                    #pragma unroll
                    for(int i = 0; i < 4; i++){
                        float xf[8]; ld8(xbuf + (b0 + i) * 1024 + ks * 256 + k, xf);
                        gx[i] = dot8(wf, xf, gx[i]);
                    }
                }
                for(int k = 0; k < 256; k += 8){
                    float wf[8]; ld8(whr + k, wf);
                    #pragma unroll
                    for(int i = 0; i < 4; i++){
                        float hf[8]; ld8(hp + (b0 + i) * 1024 + ks * 256 + k, hf);
                        gh[i] = dot8(wf, hf, gh[i]);
                    }
                }
                float dx[4] = {0,0,0,0}, dh[4] = {0,0,0,0}, db[4] = {0,0,0,0};
                int e0 = ks * 16;
                for(int e = e0; e < e0 + 16; e++){
                    float pxv = sP[0][g][e][hh];
                    float phv = sP[1][g][e][hh];
                    float pbv = sP[2][g][e][hh];
                    int zc = g * 64 + e;
                    #pragma unroll
                    for(int i = 0; i < 4; i++){
                        int b = b0 + i;
                        dx[i] += z[(b) * 256 + zc] * pxv;
                        dh[i] += z[(64 + b) * 256 + zc] * phv;
                        db[i] += z[(128 + b) * 256 + zc] * pbv;
                    }
                }
                #pragma unroll
                for(int i = 0; i < 4; i++){
                    gx[i] += __shfl_xor(gx[i], 1); gx[i] += __shfl_xor(gx[i], 2);
                    gh[i] += __shfl_xor(gh[i], 1); gh[i] += __shfl_xor(gh[i], 2);
                    dx[i] += __shfl_xor(dx[i], 1); dx[i] += __shfl_xor(dx[i], 2);
                    dh[i] += __shfl_xor(dh[i], 1); dh[i] += __shfl_xor(dh[i], 2);
                    db[i] += __shfl_xor(db[i], 1); db[i] += __shfl_xor(db[i], 2);
                }
                if(ks == 0){
                    #pragma unroll
                    for(int i = 0; i < 4; i++)
                        spre[r16 * 64 + b0 + i] = dx[i] * gx[i] + dh[i] * gh[i] + db[i];
                }
            }
            __syncthreads();
            if(tid < 256){
                int hh = tid >> 6, b = tid & 63;
                float pi_ = spre[(0 * 4 + hh) * 64 + b];
                float pf_ = spre[(1 * 4 + hh) * 64 + b];
                float pg_ = spre[(2 * 4 + hh) * 64 + b];
                float po_ = spre[(3 * 4 + hh) * 64 + b];
                int h = bid * 4 + hh;
                int idx = b * 1024 + h;
                float c2 = sigf(pf_) * cst[idx] + sigf(pi_) * tanhf(pg_);
                float h2 = sigf(po_) * tanhf(c2);
                cst[idx] = c2;
                hn[idx] = h2;
                stT(&out[((size_t)b * Tt + t) * Dd + h], h2);
            }
            grid.sync();

            float* tp = hp; hp = hn; hn = tp;
            tp = mp; mp = mn; mn = tp;
        }
    }
}

static void launch_bf16(void* const* d_in, void* d_out, float* ws, int* flag, hipStream_t stream){
    const unsigned short* xp   = (const unsigned short*)d_in[0];
    const unsigned short* Wxp  = (const unsigned short*)d_in[1];
    const unsigned short* Whp  = (const unsigned short*)d_in[2];
    const unsigned short* Wmxp = (const unsigned short*)d_in[3];
    const unsigned short* Wmhp = (const unsigned short*)d_in[4];
    const unsigned short* bmp  = (const unsigned short*)d_in[5];
    const unsigned short* Wzxp = (const unsigned short*)d_in[6];
    const unsigned short* bzxp = (const unsigned short*)d_in[7];
    const unsigned short* Wzhp = (const unsigned short*)d_in[8];
    const unsigned short* bzhp = (const unsigned short*)d_in[9];
    const unsigned short* Wzbp = (const unsigned short*)d_in[10];
    const unsigned short* Pxp  = (const unsigned short*)d_in[11];
    const unsigned short* Php  = (const unsigned short*)d_in[12];
    const unsigned short* Pbp  = (const unsigned short*)d_in[13];
    unsigned short* outp = (unsigned short*)d_out;
    void* args[] = {
        (void*)&xp, (void*)&Wxp, (void*)&Whp, (void*)&Wmxp, (void*)&Wmhp, (void*)&bmp,
        (void*)&Wzxp, (void*)&bzxp, (void*)&Wzhp, (void*)&bzhp, (void*)&Wzbp,
        (void*)&Pxp, (void*)&Php, (void*)&Pbp, (void*)&outp, (void*)&ws, (void*)&flag
    };
    hipLaunchCooperativeKernel((void*)coop_rnn_bf16, dim3(256), dim3(1024), args, 0, stream);
}

static void launch_f32(void* const* d_in, void* d_out, float* ws, int* flag, hipStream_t stream){
    const float* xp   = (const float*)d_in[0];
    const float* Wxp  = (const float*)d_in[1];
    const float* Whp  = (const float*)d_in[2];
    const float* Wmxp = (const float*)d_in[3];
    const float* Wmhp = (const float*)d_in[4];
    const float* bmp  = (const float*)d_in[5];
    const float* Wzxp = (const float*)d_in[6];
    const float* bzxp = (const float*)d_in[7];
    const float* Wzhp = (const float*)d_in[8];
    const float* bzhp = (const float*)d_in[9];
    const float* Wzbp = (const float*)d_in[10];
    const float* Pxp  = (const float*)d_in[11];
    const float* Php  = (const float*)d_in[12];
    const float* Pbp  = (const float*)d_in[13];
    float* outp = (float*)d_out;
    void* args[] = {
        (void*)&xp, (void*)&Wxp, (void*)&Whp, (void*)&Wmxp, (void*)&Wmhp, (void*)&bmp,
        (void*)&Wzxp, (void*)&bzxp, (void*)&Wzhp, (void*)&bzhp, (void*)&Wzbp,
        (void*)&Pxp, (void*)&Php, (void*)&Pbp, (void*)&outp, (void*)&ws, (void*)&flag
    };
    hipLaunchCooperativeKernel((void*)coop_rnn_f32, dim3(256), dim3(1024), args, 0, stream);
}

extern "C" void kernel_launch(void* const* d_in, const int* in_sizes, int n_in,
                              void* d_out, int out_size, void* d_ws, size_t ws_size,
                              hipStream_t stream) {
    (void)in_sizes; (void)n_in; (void)out_size; (void)ws_size;
    float* ws = (float*)d_ws;
    int* flag = (int*)(ws + 360448);

    k_detect<<<1, 64, 0, stream>>>((const unsigned short*)d_in[0], flag);
    launch_bf16(d_in, d_out, ws, flag, stream);
    launch_f32(d_in, d_out, ws, flag, stream);
}